// Round 8
// baseline (7004.791 us; speedup 1.0000x reference)
//
#include <hip/hip_runtime.h>
#include <math.h>

#define HID 128

typedef _Float16 f16x8 __attribute__((ext_vector_type(8)));
typedef float    f32x4 __attribute__((ext_vector_type(4)));

static __device__ __forceinline__ float h_lo(unsigned p) {
    return (float)__builtin_bit_cast(_Float16, (unsigned short)p);
}
static __device__ __forceinline__ float h_hi(unsigned p) {
    return (float)__builtin_bit_cast(_Float16, (unsigned short)(p >> 16));
}
static __device__ __forceinline__ unsigned pack2h(float x, float y) {
    const unsigned short lx = __builtin_bit_cast(unsigned short, (_Float16)x);
    const unsigned short ly = __builtin_bit_cast(unsigned short, (_Float16)y);
    return ((unsigned)ly << 16) | lx;
}

// ---------------------------------------------------------------------------
// Kernel 0: pack ALL GEMM weights into fp16 MFMA B-fragment order.
// B-frag layout: [NT][KK][64 lane][8 j]; elem = W[k = KK*32+(ln>>4)*8+j][n = NT*16+(ln&15)]
// regions: wqkvp 3x[24][4] | wop 3x[8][4] | w1p [8][8] | w2p [4][4] | wprojp [8][5]
// ---------------------------------------------------------------------------
__global__ __launch_bounds__(256) void prep_kernel(
    const float* __restrict__ Wqkv, const float* __restrict__ Wo,
    const float* __restrict__ W1, const float* __restrict__ W2,
    const float* __restrict__ Wproj,
    _Float16* __restrict__ dst)
{
    const int idx = blockIdx.x * 256 + threadIdx.x;
    if (idx < 147456) {                     // wqkvp: 3 layers x 24nt x 4kk
        const int l = idx / 49152, t = idx % 49152;
        const int j = t & 7, ln = (t >> 3) & 63, kk = (t >> 9) & 3, nt = t >> 11;
        const int k = kk * 32 + (ln >> 4) * 8 + j, n = nt * 16 + (ln & 15);
        dst[idx] = (_Float16)Wqkv[((size_t)l * 128 + k) * 384 + n];
    } else if (idx < 196608) {              // wop: 3 layers x 8nt x 4kk
        const int t0 = idx - 147456;
        const int l = t0 / 16384, t = t0 % 16384;
        const int j = t & 7, ln = (t >> 3) & 63, kk = (t >> 9) & 3, nt = t >> 11;
        const int k = kk * 32 + (ln >> 4) * 8 + j, n = nt * 16 + (ln & 15);
        dst[idx] = (_Float16)Wo[((size_t)l * 128 + k) * 128 + n];
    } else if (idx < 229376) {              // w1p: 8nt x 8kk (k<256)
        const int t = idx - 196608;
        const int j = t & 7, ln = (t >> 3) & 63, kk = (t >> 9) & 7, nt = t >> 12;
        const int k = kk * 32 + (ln >> 4) * 8 + j, n = nt * 16 + (ln & 15);
        dst[idx] = (_Float16)W1[k * 128 + n];
    } else if (idx < 237568) {              // w2p: 4nt x 4kk
        const int t = idx - 229376;
        const int j = t & 7, ln = (t >> 3) & 63, kk = (t >> 9) & 3, nt = t >> 11;
        const int k = kk * 32 + (ln >> 4) * 8 + j, n = nt * 16 + (ln & 15);
        dst[idx] = (_Float16)W2[k * 64 + n];
    } else if (idx < 258048) {              // wprojp: 8nt x 5kk (k<160)
        const int t = idx - 237568;
        const int j = t & 7, ln = (t >> 3) & 63;
        const int blk = t >> 9;             // nt*5 + kk
        const int kk = blk % 5, nt = blk / 5;
        const int k = kk * 32 + (ln >> 4) * 8 + j, n = nt * 16 + (ln & 15);
        dst[idx] = (_Float16)Wproj[k * 128 + n];
    }
}

// tile swizzle: byte addr = row*256 + ((col*2) ^ (row<<4)), rows 0..15, cols 0..127
// full-coverage coalesced tile->global write, parameterized row stride (halves).
#define TILE_STORE_S(dst, rowstride)                                           \
    _Pragma("unroll")                                                          \
    for (int t = 0; t < 4; ++t) {                                              \
        const int lr  = t * 4 + (lane >> 4);                                   \
        const int j16 = lane & 15;                                             \
        const f16x8 v = *(const f16x8*)(tb + lr * 256 + ((j16 * 16) ^ (lr << 4))); \
        if (base + lr < n)                                                     \
            *(f16x8*)((dst) + (size_t)(base + lr) * (rowstride) + j16 * 8) = v;\
    }

// qkv GEMM from A-frags a2[4] (K=128) -> q (stride 128) + interleaved kv rows
// kvh[node][0..127]=k, [128..255]=v  (one 512B row per node)
#define QKV_PHASE(A2, WQ, BQKV)                                                \
    {                                                                          \
        _Pragma("unroll")                                                      \
        for (int part = 0; part < 3; ++part) {                                 \
            f32x4 C[8];                                                        \
            _Pragma("unroll")                                                  \
            for (int nt = 0; nt < 8; ++nt) C[nt] = (f32x4){0.f, 0.f, 0.f, 0.f};\
            _Pragma("unroll")                                                  \
            for (int kk = 0; kk < 4; ++kk) {                                   \
                _Pragma("unroll")                                              \
                for (int nt = 0; nt < 8; ++nt) {                               \
                    const f16x8 bf = *(const f16x8*)((WQ) + (((part * 8 + nt) * 4 + kk) << 9) + lane * 8); \
                    C[nt] = __builtin_amdgcn_mfma_f32_16x16x32_f16((A2)[kk], bf, C[nt], 0, 0, 0); \
                }                                                              \
            }                                                                  \
            _Pragma("unroll")                                                  \
            for (int nt = 0; nt < 8; ++nt) {                                   \
                const int nn = nt * 16 + c;                                    \
                const float bb = (BQKV)[part * 128 + nn];                      \
                _Pragma("unroll")                                              \
                for (int r = 0; r < 4; ++r) {                                  \
                    const int rr = g * 4 + r;                                  \
                    *(_Float16*)(tb + rr * 256 + ((nn * 2) ^ (rr << 4))) = (_Float16)(C[nt][r] + bb); \
                }                                                              \
            }                                                                  \
            if (part == 0)      { TILE_STORE_S(qh, 128) }                      \
            else if (part == 1) { TILE_STORE_S(kvh, 256) }                     \
            else                { TILE_STORE_S(kvh + 128, 256) }               \
        }                                                                      \
    }

// ---------------------------------------------------------------------------
// Kernel 1: FUSED node-encode + layer-0 qkv.  Wave = 16 nodes.
// ---------------------------------------------------------------------------
__global__ __launch_bounds__(256) void encode_qkv_kernel(
    const int* __restrict__ type_idx, const int* __restrict__ cat_idx,
    const float* __restrict__ log_deg,
    const float* __restrict__ type_embed, const float* __restrict__ cat0,
    const float* __restrict__ cat1, const float* __restrict__ deg_W,
    const float* __restrict__ deg_b,
    const _Float16* __restrict__ wprojp, const float* __restrict__ proj_b,
    const _Float16* __restrict__ wq, const float* __restrict__ bqkv,
    _Float16* __restrict__ xh,
    _Float16* __restrict__ qh, _Float16* __restrict__ kvh,
    int n)
{
    __shared__ __align__(16) _Float16 tile[4][16 * 128];
    const int wave = threadIdx.x >> 6;
    const int lane = threadIdx.x & 63;
    const int g = lane >> 4, c = lane & 15;
    const int base = (blockIdx.x * 4 + wave) * 16;
    if (base >= n) return;
    const int arow = min(base + c, n - 1);
    char* const tb = (char*)&tile[wave][0];

    // ---- build A-frags for K=160 feats
    const int  ti = type_idx[arow];
    const int  c0 = cat_idx[arow * 2 + 0];
    const int  c1 = cat_idx[arow * 2 + 1];
    const float ld = log_deg[arow];
    f16x8 a[5];
    {
        const float* srcs[4] = {
            type_embed + ti * 64 + g * 8,        // kk=0: feats[0..31]
            type_embed + ti * 64 + 32 + g * 8,   // kk=1: feats[32..63]
            cat0 + c0 * 32 + g * 8,              // kk=2: feats[64..95]
            cat1 + c1 * 32 + g * 8,              // kk=3: feats[96..127]
        };
        #pragma unroll
        for (int kk = 0; kk < 4; ++kk) {
            const float4 v0 = *(const float4*)(srcs[kk]);
            const float4 v1 = *(const float4*)(srcs[kk] + 4);
            a[kk] = (f16x8){(_Float16)v0.x, (_Float16)v0.y, (_Float16)v0.z, (_Float16)v0.w,
                            (_Float16)v1.x, (_Float16)v1.y, (_Float16)v1.z, (_Float16)v1.w};
        }
        const float4 w0 = *(const float4*)(deg_W + g * 8);
        const float4 w1 = *(const float4*)(deg_W + g * 8 + 4);
        const float4 d0 = *(const float4*)(deg_b + g * 8);
        const float4 d1 = *(const float4*)(deg_b + g * 8 + 4);
        a[4] = (f16x8){
            (_Float16)fmaxf(ld * w0.x + d0.x, 0.f), (_Float16)fmaxf(ld * w0.y + d0.y, 0.f),
            (_Float16)fmaxf(ld * w0.z + d0.z, 0.f), (_Float16)fmaxf(ld * w0.w + d0.w, 0.f),
            (_Float16)fmaxf(ld * w1.x + d1.x, 0.f), (_Float16)fmaxf(ld * w1.y + d1.y, 0.f),
            (_Float16)fmaxf(ld * w1.z + d1.z, 0.f), (_Float16)fmaxf(ld * w1.w + d1.w, 0.f)};
    }

    // ---- proj: 5kk x 8nt MFMAs
    f32x4 Cp[8];
    #pragma unroll
    for (int nt = 0; nt < 8; ++nt) Cp[nt] = (f32x4){0.f, 0.f, 0.f, 0.f};
    #pragma unroll
    for (int kk = 0; kk < 5; ++kk) {
        #pragma unroll
        for (int nt = 0; nt < 8; ++nt) {
            const f16x8 bf = *(const f16x8*)(wprojp + ((nt * 5 + kk) << 9) + lane * 8);
            Cp[nt] = __builtin_amdgcn_mfma_f32_16x16x32_f16(a[kk], bf, Cp[nt], 0, 0, 0);
        }
    }
    #pragma unroll
    for (int nt = 0; nt < 8; ++nt) {
        const int nn = nt * 16 + c;
        const float bb = proj_b[nn];
        #pragma unroll
        for (int r = 0; r < 4; ++r) {
            const int rr = g * 4 + r;
            *(_Float16*)(tb + rr * 256 + ((nn * 2) ^ (rr << 4))) = (_Float16)(Cp[nt][r] + bb);
        }
    }
    TILE_STORE_S(xh, 128)

    // ---- layer-0 qkv from the tile
    f16x8 a2[4];
    #pragma unroll
    for (int kk = 0; kk < 4; ++kk)
        a2[kk] = *(const f16x8*)(tb + c * 256 + ((kk * 64 + g * 16) ^ (c << 4)));
    QKV_PHASE(a2, wq, bqkv)
}

// ---------------------------------------------------------------------------
// Kernel 2: fused out-proj (+fallback+relu) and optional next-layer qkv.
// ---------------------------------------------------------------------------
__global__ __launch_bounds__(256) void projqkv_kernel(
    const _Float16* __restrict__ oh, const int* __restrict__ mask,
    const _Float16* __restrict__ xh_prev,
    const _Float16* __restrict__ wo, const float* __restrict__ bo,
    const _Float16* __restrict__ wq, const float* __restrict__ bqkv,
    _Float16* __restrict__ xh_next,
    _Float16* __restrict__ qh, _Float16* __restrict__ kvh,
    int do_qkv, int n)
{
    __shared__ __align__(16) _Float16 tile[4][16 * 128];
    const int wave = threadIdx.x >> 6;
    const int lane = threadIdx.x & 63;
    const int g = lane >> 4, c = lane & 15;
    const int base = (blockIdx.x * 4 + wave) * 16;
    if (base >= n) return;
    const int arow = min(base + c, n - 1);
    char* const tb = (char*)&tile[wave][0];

    // ---- phase 1: o @ Wo
    f32x4 Cp[8];
    #pragma unroll
    for (int nt = 0; nt < 8; ++nt) Cp[nt] = (f32x4){0.f, 0.f, 0.f, 0.f};
    #pragma unroll
    for (int kk = 0; kk < 4; ++kk) {
        const f16x8 a = *(const f16x8*)(oh + (size_t)arow * 128 + kk * 32 + g * 8);
        #pragma unroll
        for (int nt = 0; nt < 8; ++nt) {
            const f16x8 bf = *(const f16x8*)(wo + ((nt * 4 + kk) << 9) + lane * 8);
            Cp[nt] = __builtin_amdgcn_mfma_f32_16x16x32_f16(a, bf, Cp[nt], 0, 0, 0);
        }
    }
    int mk[4]; int rrow[4];
    #pragma unroll
    for (int r = 0; r < 4; ++r) {
        rrow[r] = min(base + g * 4 + r, n - 1);
        mk[r] = mask[rrow[r]];
    }
    #pragma unroll
    for (int nt = 0; nt < 8; ++nt) {
        const int nn = nt * 16 + c;
        const float bb = bo[nn];
        #pragma unroll
        for (int r = 0; r < 4; ++r) {
            float val = Cp[nt][r] + bb;
            if (!mk[r]) val = (float)xh_prev[(size_t)rrow[r] * 128 + nn];
            val = fmaxf(val, 0.0f);
            const int rr = g * 4 + r;
            *(_Float16*)(tb + rr * 256 + ((nn * 2) ^ (rr << 4))) = (_Float16)val;
        }
    }
    // write x_next coalesced (full 128 cols)
    TILE_STORE_S(xh_next, 128)
    if (!do_qkv) return;

    // ---- phase 2: x_next @ Wqkv (A-frags read from tile BEFORE overwriting it)
    f16x8 a2[4];
    #pragma unroll
    for (int kk = 0; kk < 4; ++kk)
        a2[kk] = *(const f16x8*)(tb + c * 256 + ((kk * 64 + g * 16) ^ (c << 4)));
    QKV_PHASE(a2, wq, bqkv)
}

// ---------------------------------------------------------------------------
// Kernel 3: attention core: scores + softmax + PV.  Writes o (fp16) + mask.
// Wave per node.  Invalid-neighbor gathers are SKIPPED via wave-uniform branch
// (nbr_mask is uniform across the wave -> s_cbranch_execz, no divergence);
// ~47% of gather bytes eliminated, math unchanged (invalid slots were exact 0).
// ---------------------------------------------------------------------------
__global__ __launch_bounds__(256) void attn_kernel(
    const _Float16* __restrict__ qh, const _Float16* __restrict__ kvh,
    const int* __restrict__ nbr_idx, const int* __restrict__ nbr_mask,
    _Float16* __restrict__ oh, int* __restrict__ mask_out, int n)
{
    const int wave = threadIdx.x >> 6;
    const int lane = threadIdx.x & 63;
    const float scale = 0.17677669529663687f;   // 1/sqrt(32)
    const int node = blockIdx.x * 4 + wave;
    if (node >= n) return;

    const unsigned qq = *(const unsigned*)(qh + (size_t)node * HID + lane * 2);
    const float qx = h_lo(qq), qy = h_hi(qq);

    unsigned kw[17], vw[17];
    int valid[17];
    valid[0] = 1;
    {
        const _Float16* kv = kvh + (size_t)node * 256;
        kw[0] = *(const unsigned*)(kv + lane * 2);
        vw[0] = *(const unsigned*)(kv + 128 + lane * 2);
    }
    int anyn = 0;
    #pragma unroll
    for (int c = 1; c < 17; ++c) {
        const int cidx = nbr_idx[node * 16 + (c - 1)];
        const int vld  = nbr_mask[node * 16 + (c - 1)];
        valid[c] = vld;
        anyn |= vld;
        kw[c] = 0u;
        vw[c] = 0u;
        if (vld) {                                   // wave-uniform branch
            const _Float16* kv = kvh + (size_t)cidx * 256;
            kw[c] = *(const unsigned*)(kv + lane * 2);
            vw[c] = *(const unsigned*)(kv + 128 + lane * 2);
        }
    }
    if (lane == 0) mask_out[node] = anyn;

    float s[17];
    #pragma unroll
    for (int c = 0; c < 17; ++c) {
        float p = qx * h_lo(kw[c]) + qy * h_hi(kw[c]);
        p += __shfl_xor(p, 1);
        p += __shfl_xor(p, 2);
        p += __shfl_xor(p, 4);
        p += __shfl_xor(p, 8);
        s[c] = valid[c] ? p * scale : -1e9f;
    }
    float mx = s[0];
    #pragma unroll
    for (int c = 1; c < 17; ++c) mx = fmaxf(mx, s[c]);
    float sum = 0.0f;
    #pragma unroll
    for (int c = 0; c < 17; ++c) { s[c] = __expf(s[c] - mx); sum += s[c]; }
    const float inv = 1.0f / sum;
    float ox = 0.0f, oy = 0.0f;
    #pragma unroll
    for (int c = 0; c < 17; ++c) {
        const float a = s[c] * inv;
        ox += a * h_lo(vw[c]);
        oy += a * h_hi(vw[c]);
    }
    *(unsigned*)(oh + (size_t)node * HID + lane * 2) = pack2h(ox, oy);
}

// ---------------------------------------------------------------------------
// Kernel 4: edge MLP via fp16 MFMA.
// ---------------------------------------------------------------------------
__global__ __launch_bounds__(256) void edge_mfma_kernel(
    const _Float16* __restrict__ xh,          // [N][128] fp16 final x
    const int* __restrict__ edges,
    const float* __restrict__ edge_feats,
    const _Float16* __restrict__ w1p,         // packed B-frags, 32768
    const _Float16* __restrict__ w2p,         // packed B-frags, 8192
    const float* __restrict__ W1,             // fp32 (rows 256,257 used)
    const float* __restrict__ b1,
    const float* __restrict__ b2,
    const float* __restrict__ W3, const float* __restrict__ b3,
    float* __restrict__ out, int ne)
{
    __shared__ __align__(16) _Float16 h1s[4][16 * 128];
    const int wave = threadIdx.x >> 6;
    const int lane = threadIdx.x & 63;
    const int g = lane >> 4, c = lane & 15;
    const int base = (blockIdx.x * 4 + wave) * 16;
    if (base >= ne) return;

    const int erow = min(base + c, ne - 1);
    const int e0 = edges[erow * 2 + 0];
    const int e1 = edges[erow * 2 + 1];

    // ---- layer 1: [16,256] x [256,128]
    f32x4 C1[8];
    #pragma unroll
    for (int nt = 0; nt < 8; ++nt) C1[nt] = (f32x4){0.f, 0.f, 0.f, 0.f};
    #pragma unroll
    for (int kk = 0; kk < 8; ++kk) {
        const int node = (kk < 4) ? e0 : e1;
        const f16x8 a = *(const f16x8*)(xh + (size_t)node * 128 + (kk & 3) * 32 + g * 8);
        #pragma unroll
        for (int nt = 0; nt < 8; ++nt) {
            const f16x8 bf = *(const f16x8*)(w1p + ((nt * 8 + kk) << 9) + lane * 8);
            C1[nt] = __builtin_amdgcn_mfma_f32_16x16x32_f16(a, bf, C1[nt], 0, 0, 0);
        }
    }

    // ---- epilogue 1: + b1 + ef @ W1[256:258] ; relu ; fp16 -> swizzled LDS
    float ef0[4], ef1[4];
    #pragma unroll
    for (int r = 0; r < 4; ++r) {
        const int m = min(base + g * 4 + r, ne - 1);
        ef0[r] = edge_feats[(size_t)m * 2 + 0];
        ef1[r] = edge_feats[(size_t)m * 2 + 1];
    }
    char* const h1base = (char*)&h1s[wave][0];
    #pragma unroll
    for (int nt = 0; nt < 8; ++nt) {
        const int nn  = nt * 16 + c;
        const float bb  = b1[nn];
        const float wc0 = W1[256 * 128 + nn];
        const float wc1 = W1[257 * 128 + nn];
        #pragma unroll
        for (int r = 0; r < 4; ++r) {
            const int rr = g * 4 + r;
            const float h = fmaxf(C1[nt][r] + bb + ef0[r] * wc0 + ef1[r] * wc1, 0.0f);
            *(_Float16*)(h1base + rr * 256 + ((nn * 2) ^ (rr << 4))) = (_Float16)h;
        }
    }

    // ---- layer 2: [16,128] x [128,64]
    f32x4 C2[4];
    #pragma unroll
    for (int nt = 0; nt < 4; ++nt) C2[nt] = (f32x4){0.f, 0.f, 0.f, 0.f};
    #pragma unroll
    for (int kk = 0; kk < 4; ++kk) {
        const int k0b = kk * 64 + g * 16;
        const f16x8 a = *(const f16x8*)(h1base + c * 256 + (k0b ^ (c << 4)));
        #pragma unroll
        for (int nt = 0; nt < 4; ++nt) {
            const f16x8 bf = *(const f16x8*)(w2p + ((nt * 4 + kk) << 9) + lane * 8);
            C2[nt] = __builtin_amdgcn_mfma_f32_16x16x32_f16(a, bf, C2[nt], 0, 0, 0);
        }
    }

    // ---- layer 3: relu(h2) @ W3 + b3, 16-lane tree reduce
    const float bb3 = b3[0];
    #pragma unroll
    for (int r = 0; r < 4; ++r) {
        float acc = 0.0f;
        #pragma unroll
        for (int nt = 0; nt < 4; ++nt) {
            const int n2 = nt * 16 + c;
            acc += fmaxf(C2[nt][r] + b2[n2], 0.0f) * W3[n2];
        }
        acc += __shfl_xor(acc, 1);
        acc += __shfl_xor(acc, 2);
        acc += __shfl_xor(acc, 4);
        acc += __shfl_xor(acc, 8);
        const int m = base + g * 4 + r;
        if (c == 0 && m < ne) out[m] = acc + bb3;
    }
}

// ---------------------------------------------------------------------------
extern "C" void kernel_launch(void* const* d_in, const int* in_sizes, int n_in,
                              void* d_out, int out_size, void* d_ws, size_t ws_size,
                              hipStream_t stream) {
    const int*   type_idx   = (const int*)d_in[0];
    const int*   cat_idx    = (const int*)d_in[1];
    const int*   nbr_idx    = (const int*)d_in[2];
    const int*   nbr_mask   = (const int*)d_in[3];
    const int*   edges      = (const int*)d_in[4];
    const float* log_deg    = (const float*)d_in[5];
    const float* edge_feats = (const float*)d_in[6];
    const float* type_embed = (const float*)d_in[7];
    const float* cat0       = (const float*)d_in[8];
    const float* cat1       = (const float*)d_in[9];
    const float* deg_W      = (const float*)d_in[10];
    const float* deg_b      = (const float*)d_in[11];
    const float* proj_W     = (const float*)d_in[12];
    const float* proj_b     = (const float*)d_in[13];
    const float* attn_Wqkv  = (const float*)d_in[14];
    const float* attn_bqkv  = (const float*)d_in[15];
    const float* attn_Wo    = (const float*)d_in[16];
    const float* attn_bo    = (const float*)d_in[17];
    const float* eW1        = (const float*)d_in[18];
    const float* eb1        = (const float*)d_in[19];
    const float* eW2        = (const float*)d_in[20];
    const float* eb2        = (const float*)d_in[21];
    const float* eW3        = (const float*)d_in[22];
    const float* eb3        = (const float*)d_in[23];

    const int n  = in_sizes[0];        // N nodes
    const int ne = in_sizes[4] / 2;    // E edges
    float* out = (float*)d_out;

    // fp16 workspace buffers
    _Float16* xhA = (_Float16*)d_ws;                 // n*128
    _Float16* xhB = xhA + (size_t)n * HID;           // n*128
    _Float16* qh  = xhB + (size_t)n * HID;           // n*128
    _Float16* kvh = qh  + (size_t)n * HID;           // n*256 (k|v interleaved)
    _Float16* oh  = kvh + (size_t)n * 256;           // n*128
    _Float16* wpk = oh  + (size_t)n * HID;           // packed weights, 258048 halves
    int* mask = (int*)(wpk + 258048);
    _Float16* wqkvp[3] = {wpk, wpk + 49152, wpk + 98304};
    _Float16* wop[3]   = {wpk + 147456, wpk + 163840, wpk + 180224};
    _Float16* w1p    = wpk + 196608;
    _Float16* w2p    = wpk + 229376;
    _Float16* wprojp = wpk + 237568;

    prep_kernel<<<dim3(1008), dim3(256), 0, stream>>>(
        attn_Wqkv, attn_Wo, eW1, eW2, proj_W, wpk);

    const int gemm_grid = (n + 63) / 64;    // 4 waves x 16 nodes
    const int attn_grid = (n + 3) / 4;      // 4 waves x 1 node

    // fused encode + layer-0 qkv
    encode_qkv_kernel<<<dim3(gemm_grid), dim3(256), 0, stream>>>(
        type_idx, cat_idx, log_deg, type_embed, cat0, cat1, deg_W, deg_b,
        wprojp, proj_b, wqkvp[0], attn_bqkv,
        xhA, qh, kvh, n);
    attn_kernel<<<dim3(attn_grid), dim3(256), 0, stream>>>(
        qh, kvh, nbr_idx, nbr_mask, oh, mask, n);

    // layer transitions: (oh,mask,x_prev) -> x_next (+ qkv for next layer)
    projqkv_kernel<<<dim3(gemm_grid), dim3(256), 0, stream>>>(
        oh, mask, xhA, wop[0], attn_bo, wqkvp[1], attn_bqkv + 384,
        xhB, qh, kvh, 1, n);
    attn_kernel<<<dim3(attn_grid), dim3(256), 0, stream>>>(
        qh, kvh, nbr_idx, nbr_mask, oh, mask, n);

    projqkv_kernel<<<dim3(gemm_grid), dim3(256), 0, stream>>>(
        oh, mask, xhB, wop[1], attn_bo + 128, wqkvp[2], attn_bqkv + 768,
        xhA, qh, kvh, 1, n);
    attn_kernel<<<dim3(attn_grid), dim3(256), 0, stream>>>(
        qh, kvh, nbr_idx, nbr_mask, oh, mask, n);

    projqkv_kernel<<<dim3(gemm_grid), dim3(256), 0, stream>>>(
        oh, mask, xhA, wop[2], attn_bo + 256, nullptr, nullptr,
        xhB, nullptr, nullptr, 0, n);

    const int edge_grid = (ne + 63) / 64;   // 4 waves x 16 edges
    edge_mfma_kernel<<<dim3(edge_grid), dim3(256), 0, stream>>>(
        xhB, edges, edge_feats, w1p, w2p, eW1, eb1, eb2, eW3, eb3, out, ne);
}

// Round 9
// 4087.394 us; speedup vs baseline: 1.7138x; 1.7138x over previous
//
#include <hip/hip_runtime.h>
#include <math.h>

#define HID 128

typedef _Float16 f16x8 __attribute__((ext_vector_type(8)));
typedef float    f32x4 __attribute__((ext_vector_type(4)));

static __device__ __forceinline__ float h_lo(unsigned p) {
    return (float)__builtin_bit_cast(_Float16, (unsigned short)p);
}
static __device__ __forceinline__ float h_hi(unsigned p) {
    return (float)__builtin_bit_cast(_Float16, (unsigned short)(p >> 16));
}
static __device__ __forceinline__ unsigned pack2h(float x, float y) {
    const unsigned short lx = __builtin_bit_cast(unsigned short, (_Float16)x);
    const unsigned short ly = __builtin_bit_cast(unsigned short, (_Float16)y);
    return ((unsigned)ly << 16) | lx;
}

// ---------------------------------------------------------------------------
// Kernel 0: pack ALL GEMM weights into fp16 MFMA B-fragment order.
// B-frag layout: [NT][KK][64 lane][8 j]; elem = W[k = KK*32+(ln>>4)*8+j][n = NT*16+(ln&15)]
// regions: wqkvp 3x[24][4] | wop 3x[8][4] | w1p [8][8] | w2p [4][4] | wprojp [8][5]
// ---------------------------------------------------------------------------
__global__ __launch_bounds__(256) void prep_kernel(
    const float* __restrict__ Wqkv, const float* __restrict__ Wo,
    const float* __restrict__ W1, const float* __restrict__ W2,
    const float* __restrict__ Wproj,
    _Float16* __restrict__ dst)
{
    const int idx = blockIdx.x * 256 + threadIdx.x;
    if (idx < 147456) {                     // wqkvp: 3 layers x 24nt x 4kk
        const int l = idx / 49152, t = idx % 49152;
        const int j = t & 7, ln = (t >> 3) & 63, kk = (t >> 9) & 3, nt = t >> 11;
        const int k = kk * 32 + (ln >> 4) * 8 + j, n = nt * 16 + (ln & 15);
        dst[idx] = (_Float16)Wqkv[((size_t)l * 128 + k) * 384 + n];
    } else if (idx < 196608) {              // wop: 3 layers x 8nt x 4kk
        const int t0 = idx - 147456;
        const int l = t0 / 16384, t = t0 % 16384;
        const int j = t & 7, ln = (t >> 3) & 63, kk = (t >> 9) & 3, nt = t >> 11;
        const int k = kk * 32 + (ln >> 4) * 8 + j, n = nt * 16 + (ln & 15);
        dst[idx] = (_Float16)Wo[((size_t)l * 128 + k) * 128 + n];
    } else if (idx < 229376) {              // w1p: 8nt x 8kk (k<256)
        const int t = idx - 196608;
        const int j = t & 7, ln = (t >> 3) & 63, kk = (t >> 9) & 7, nt = t >> 12;
        const int k = kk * 32 + (ln >> 4) * 8 + j, n = nt * 16 + (ln & 15);
        dst[idx] = (_Float16)W1[k * 128 + n];
    } else if (idx < 237568) {              // w2p: 4nt x 4kk
        const int t = idx - 229376;
        const int j = t & 7, ln = (t >> 3) & 63, kk = (t >> 9) & 3, nt = t >> 11;
        const int k = kk * 32 + (ln >> 4) * 8 + j, n = nt * 16 + (ln & 15);
        dst[idx] = (_Float16)W2[k * 64 + n];
    } else if (idx < 258048) {              // wprojp: 8nt x 5kk (k<160)
        const int t = idx - 237568;
        const int j = t & 7, ln = (t >> 3) & 63;
        const int blk = t >> 9;             // nt*5 + kk
        const int kk = blk % 5, nt = blk / 5;
        const int k = kk * 32 + (ln >> 4) * 8 + j, n = nt * 16 + (ln & 15);
        dst[idx] = (_Float16)Wproj[k * 128 + n];
    }
}

// tile swizzle: byte addr = row*256 + ((col*2) ^ (row<<4)), rows 0..15, cols 0..127
// full-coverage coalesced tile->global write, parameterized row stride (halves).
#define TILE_STORE_S(dst, rowstride)                                           \
    _Pragma("unroll")                                                          \
    for (int t = 0; t < 4; ++t) {                                              \
        const int lr  = t * 4 + (lane >> 4);                                   \
        const int j16 = lane & 15;                                             \
        const f16x8 v = *(const f16x8*)(tb + lr * 256 + ((j16 * 16) ^ (lr << 4))); \
        if (base + lr < n)                                                     \
            *(f16x8*)((dst) + (size_t)(base + lr) * (rowstride) + j16 * 8) = v;\
    }

// qkv GEMM from A-frags a2[4] (K=128) -> q (stride 128) + interleaved kv rows
// kvh[node][0..127]=k, [128..255]=v  (one 512B row per node)
#define QKV_PHASE(A2, WQ, BQKV)                                                \
    {                                                                          \
        _Pragma("unroll")                                                      \
        for (int part = 0; part < 3; ++part) {                                 \
            f32x4 C[8];                                                        \
            _Pragma("unroll")                                                  \
            for (int nt = 0; nt < 8; ++nt) C[nt] = (f32x4){0.f, 0.f, 0.f, 0.f};\
            _Pragma("unroll")                                                  \
            for (int kk = 0; kk < 4; ++kk) {                                   \
                _Pragma("unroll")                                              \
                for (int nt = 0; nt < 8; ++nt) {                               \
                    const f16x8 bf = *(const f16x8*)((WQ) + (((part * 8 + nt) * 4 + kk) << 9) + lane * 8); \
                    C[nt] = __builtin_amdgcn_mfma_f32_16x16x32_f16((A2)[kk], bf, C[nt], 0, 0, 0); \
                }                                                              \
            }                                                                  \
            _Pragma("unroll")                                                  \
            for (int nt = 0; nt < 8; ++nt) {                                   \
                const int nn = nt * 16 + c;                                    \
                const float bb = (BQKV)[part * 128 + nn];                      \
                _Pragma("unroll")                                              \
                for (int r = 0; r < 4; ++r) {                                  \
                    const int rr = g * 4 + r;                                  \
                    *(_Float16*)(tb + rr * 256 + ((nn * 2) ^ (rr << 4))) = (_Float16)(C[nt][r] + bb); \
                }                                                              \
            }                                                                  \
            if (part == 0)      { TILE_STORE_S(qh, 128) }                      \
            else if (part == 1) { TILE_STORE_S(kvh, 256) }                     \
            else                { TILE_STORE_S(kvh + 128, 256) }               \
        }                                                                      \
    }

// ---------------------------------------------------------------------------
// Kernel 1: FUSED node-encode + layer-0 qkv.  Wave = 16 nodes.
// ---------------------------------------------------------------------------
__global__ __launch_bounds__(256) void encode_qkv_kernel(
    const int* __restrict__ type_idx, const int* __restrict__ cat_idx,
    const float* __restrict__ log_deg,
    const float* __restrict__ type_embed, const float* __restrict__ cat0,
    const float* __restrict__ cat1, const float* __restrict__ deg_W,
    const float* __restrict__ deg_b,
    const _Float16* __restrict__ wprojp, const float* __restrict__ proj_b,
    const _Float16* __restrict__ wq, const float* __restrict__ bqkv,
    _Float16* __restrict__ xh,
    _Float16* __restrict__ qh, _Float16* __restrict__ kvh,
    int n)
{
    __shared__ __align__(16) _Float16 tile[4][16 * 128];
    const int wave = threadIdx.x >> 6;
    const int lane = threadIdx.x & 63;
    const int g = lane >> 4, c = lane & 15;
    const int base = (blockIdx.x * 4 + wave) * 16;
    if (base >= n) return;
    const int arow = min(base + c, n - 1);
    char* const tb = (char*)&tile[wave][0];

    // ---- build A-frags for K=160 feats
    const int  ti = type_idx[arow];
    const int  c0 = cat_idx[arow * 2 + 0];
    const int  c1 = cat_idx[arow * 2 + 1];
    const float ld = log_deg[arow];
    f16x8 a[5];
    {
        const float* srcs[4] = {
            type_embed + ti * 64 + g * 8,        // kk=0: feats[0..31]
            type_embed + ti * 64 + 32 + g * 8,   // kk=1: feats[32..63]
            cat0 + c0 * 32 + g * 8,              // kk=2: feats[64..95]
            cat1 + c1 * 32 + g * 8,              // kk=3: feats[96..127]
        };
        #pragma unroll
        for (int kk = 0; kk < 4; ++kk) {
            const float4 v0 = *(const float4*)(srcs[kk]);
            const float4 v1 = *(const float4*)(srcs[kk] + 4);
            a[kk] = (f16x8){(_Float16)v0.x, (_Float16)v0.y, (_Float16)v0.z, (_Float16)v0.w,
                            (_Float16)v1.x, (_Float16)v1.y, (_Float16)v1.z, (_Float16)v1.w};
        }
        const float4 w0 = *(const float4*)(deg_W + g * 8);
        const float4 w1 = *(const float4*)(deg_W + g * 8 + 4);
        const float4 d0 = *(const float4*)(deg_b + g * 8);
        const float4 d1 = *(const float4*)(deg_b + g * 8 + 4);
        a[4] = (f16x8){
            (_Float16)fmaxf(ld * w0.x + d0.x, 0.f), (_Float16)fmaxf(ld * w0.y + d0.y, 0.f),
            (_Float16)fmaxf(ld * w0.z + d0.z, 0.f), (_Float16)fmaxf(ld * w0.w + d0.w, 0.f),
            (_Float16)fmaxf(ld * w1.x + d1.x, 0.f), (_Float16)fmaxf(ld * w1.y + d1.y, 0.f),
            (_Float16)fmaxf(ld * w1.z + d1.z, 0.f), (_Float16)fmaxf(ld * w1.w + d1.w, 0.f)};
    }

    // ---- proj: 5kk x 8nt MFMAs
    f32x4 Cp[8];
    #pragma unroll
    for (int nt = 0; nt < 8; ++nt) Cp[nt] = (f32x4){0.f, 0.f, 0.f, 0.f};
    #pragma unroll
    for (int kk = 0; kk < 5; ++kk) {
        #pragma unroll
        for (int nt = 0; nt < 8; ++nt) {
            const f16x8 bf = *(const f16x8*)(wprojp + ((nt * 5 + kk) << 9) + lane * 8);
            Cp[nt] = __builtin_amdgcn_mfma_f32_16x16x32_f16(a[kk], bf, Cp[nt], 0, 0, 0);
        }
    }
    #pragma unroll
    for (int nt = 0; nt < 8; ++nt) {
        const int nn = nt * 16 + c;
        const float bb = proj_b[nn];
        #pragma unroll
        for (int r = 0; r < 4; ++r) {
            const int rr = g * 4 + r;
            *(_Float16*)(tb + rr * 256 + ((nn * 2) ^ (rr << 4))) = (_Float16)(Cp[nt][r] + bb);
        }
    }
    TILE_STORE_S(xh, 128)

    // ---- layer-0 qkv from the tile
    f16x8 a2[4];
    #pragma unroll
    for (int kk = 0; kk < 4; ++kk)
        a2[kk] = *(const f16x8*)(tb + c * 256 + ((kk * 64 + g * 16) ^ (c << 4)));
    QKV_PHASE(a2, wq, bqkv)
}

// ---------------------------------------------------------------------------
// Kernel 2: fused out-proj (+fallback+relu) and optional next-layer qkv.
// ---------------------------------------------------------------------------
__global__ __launch_bounds__(256) void projqkv_kernel(
    const _Float16* __restrict__ oh, const int* __restrict__ mask,
    const _Float16* __restrict__ xh_prev,
    const _Float16* __restrict__ wo, const float* __restrict__ bo,
    const _Float16* __restrict__ wq, const float* __restrict__ bqkv,
    _Float16* __restrict__ xh_next,
    _Float16* __restrict__ qh, _Float16* __restrict__ kvh,
    int do_qkv, int n)
{
    __shared__ __align__(16) _Float16 tile[4][16 * 128];
    const int wave = threadIdx.x >> 6;
    const int lane = threadIdx.x & 63;
    const int g = lane >> 4, c = lane & 15;
    const int base = (blockIdx.x * 4 + wave) * 16;
    if (base >= n) return;
    const int arow = min(base + c, n - 1);
    char* const tb = (char*)&tile[wave][0];

    // ---- phase 1: o @ Wo
    f32x4 Cp[8];
    #pragma unroll
    for (int nt = 0; nt < 8; ++nt) Cp[nt] = (f32x4){0.f, 0.f, 0.f, 0.f};
    #pragma unroll
    for (int kk = 0; kk < 4; ++kk) {
        const f16x8 a = *(const f16x8*)(oh + (size_t)arow * 128 + kk * 32 + g * 8);
        #pragma unroll
        for (int nt = 0; nt < 8; ++nt) {
            const f16x8 bf = *(const f16x8*)(wo + ((nt * 4 + kk) << 9) + lane * 8);
            Cp[nt] = __builtin_amdgcn_mfma_f32_16x16x32_f16(a, bf, Cp[nt], 0, 0, 0);
        }
    }
    int mk[4]; int rrow[4];
    #pragma unroll
    for (int r = 0; r < 4; ++r) {
        rrow[r] = min(base + g * 4 + r, n - 1);
        mk[r] = mask[rrow[r]];
    }
    #pragma unroll
    for (int nt = 0; nt < 8; ++nt) {
        const int nn = nt * 16 + c;
        const float bb = bo[nn];
        #pragma unroll
        for (int r = 0; r < 4; ++r) {
            float val = Cp[nt][r] + bb;
            if (!mk[r]) val = (float)xh_prev[(size_t)rrow[r] * 128 + nn];
            val = fmaxf(val, 0.0f);
            const int rr = g * 4 + r;
            *(_Float16*)(tb + rr * 256 + ((nn * 2) ^ (rr << 4))) = (_Float16)val;
        }
    }
    // write x_next coalesced (full 128 cols)
    TILE_STORE_S(xh_next, 128)
    if (!do_qkv) return;

    // ---- phase 2: x_next @ Wqkv (A-frags read from tile BEFORE overwriting it)
    f16x8 a2[4];
    #pragma unroll
    for (int kk = 0; kk < 4; ++kk)
        a2[kk] = *(const f16x8*)(tb + c * 256 + ((kk * 64 + g * 16) ^ (c << 4)));
    QKV_PHASE(a2, wq, bqkv)
}

// ---------------------------------------------------------------------------
// Kernel 3: attention core.  Wave per node.  Invalid-neighbor gathers skipped
// via SCALAR branch: vld goes through readfirstlane -> SGPR -> s_cbranch.
// (Round 8's per-lane `if(vld)` was treated as divergent -> arrays spilled to
// scratch, 14 GB of writes.  readfirstlane is exact: all lanes read the same
// nbr_mask element.)
// ---------------------------------------------------------------------------
__global__ __launch_bounds__(256) void attn_kernel(
    const _Float16* __restrict__ qh, const _Float16* __restrict__ kvh,
    const int* __restrict__ nbr_idx, const int* __restrict__ nbr_mask,
    _Float16* __restrict__ oh, int* __restrict__ mask_out, int n)
{
    const int wave = threadIdx.x >> 6;
    const int lane = threadIdx.x & 63;
    const float scale = 0.17677669529663687f;   // 1/sqrt(32)
    const int node = blockIdx.x * 4 + wave;
    if (node >= n) return;

    const unsigned qq = *(const unsigned*)(qh + (size_t)node * HID + lane * 2);
    const float qx = h_lo(qq), qy = h_hi(qq);

    unsigned kw[17], vw[17];
    {
        const _Float16* kv = kvh + (size_t)node * 256;
        kw[0] = *(const unsigned*)(kv + lane * 2);
        vw[0] = *(const unsigned*)(kv + 128 + lane * 2);
    }
    int vbits = 1;                       // bit c set = context c valid (scalar)
    #pragma unroll
    for (int c = 1; c < 17; ++c) {
        const int vld = __builtin_amdgcn_readfirstlane(nbr_mask[node * 16 + (c - 1)]);
        kw[c] = 0u;
        vw[c] = 0u;
        if (vld) {                       // scalar branch: loads skipped entirely
            const int cidx = nbr_idx[node * 16 + (c - 1)];
            const _Float16* kv = kvh + (size_t)cidx * 256;
            kw[c] = *(const unsigned*)(kv + lane * 2);
            vw[c] = *(const unsigned*)(kv + 128 + lane * 2);
            vbits |= (1 << c);
        }
    }
    if (lane == 0) mask_out[node] = (vbits >> 1) != 0;

    float s[17];
    #pragma unroll
    for (int c = 0; c < 17; ++c) {
        float p = qx * h_lo(kw[c]) + qy * h_hi(kw[c]);
        p += __shfl_xor(p, 1);
        p += __shfl_xor(p, 2);
        p += __shfl_xor(p, 4);
        p += __shfl_xor(p, 8);
        s[c] = (vbits & (1 << c)) ? p * scale : -1e9f;
    }
    float mx = s[0];
    #pragma unroll
    for (int c = 1; c < 17; ++c) mx = fmaxf(mx, s[c]);
    float sum = 0.0f;
    #pragma unroll
    for (int c = 0; c < 17; ++c) { s[c] = __expf(s[c] - mx); sum += s[c]; }
    const float inv = 1.0f / sum;
    float ox = 0.0f, oy = 0.0f;
    #pragma unroll
    for (int c = 0; c < 17; ++c) {
        const float a = s[c] * inv;
        ox += a * h_lo(vw[c]);
        oy += a * h_hi(vw[c]);
    }
    *(unsigned*)(oh + (size_t)node * HID + lane * 2) = pack2h(ox, oy);
}

// ---------------------------------------------------------------------------
// Kernel 4: edge MLP via fp16 MFMA.
// ---------------------------------------------------------------------------
__global__ __launch_bounds__(256) void edge_mfma_kernel(
    const _Float16* __restrict__ xh,          // [N][128] fp16 final x
    const int* __restrict__ edges,
    const float* __restrict__ edge_feats,
    const _Float16* __restrict__ w1p,         // packed B-frags, 32768
    const _Float16* __restrict__ w2p,         // packed B-frags, 8192
    const float* __restrict__ W1,             // fp32 (rows 256,257 used)
    const float* __restrict__ b1,
    const float* __restrict__ b2,
    const float* __restrict__ W3, const float* __restrict__ b3,
    float* __restrict__ out, int ne)
{
    __shared__ __align__(16) _Float16 h1s[4][16 * 128];
    const int wave = threadIdx.x >> 6;
    const int lane = threadIdx.x & 63;
    const int g = lane >> 4, c = lane & 15;
    const int base = (blockIdx.x * 4 + wave) * 16;
    if (base >= ne) return;

    const int erow = min(base + c, ne - 1);
    const int e0 = edges[erow * 2 + 0];
    const int e1 = edges[erow * 2 + 1];

    // ---- layer 1: [16,256] x [256,128]
    f32x4 C1[8];
    #pragma unroll
    for (int nt = 0; nt < 8; ++nt) C1[nt] = (f32x4){0.f, 0.f, 0.f, 0.f};
    #pragma unroll
    for (int kk = 0; kk < 8; ++kk) {
        const int node = (kk < 4) ? e0 : e1;
        const f16x8 a = *(const f16x8*)(xh + (size_t)node * 128 + (kk & 3) * 32 + g * 8);
        #pragma unroll
        for (int nt = 0; nt < 8; ++nt) {
            const f16x8 bf = *(const f16x8*)(w1p + ((nt * 8 + kk) << 9) + lane * 8);
            C1[nt] = __builtin_amdgcn_mfma_f32_16x16x32_f16(a, bf, C1[nt], 0, 0, 0);
        }
    }

    // ---- epilogue 1: + b1 + ef @ W1[256:258] ; relu ; fp16 -> swizzled LDS
    float ef0[4], ef1[4];
    #pragma unroll
    for (int r = 0; r < 4; ++r) {
        const int m = min(base + g * 4 + r, ne - 1);
        ef0[r] = edge_feats[(size_t)m * 2 + 0];
        ef1[r] = edge_feats[(size_t)m * 2 + 1];
    }
    char* const h1base = (char*)&h1s[wave][0];
    #pragma unroll
    for (int nt = 0; nt < 8; ++nt) {
        const int nn  = nt * 16 + c;
        const float bb  = b1[nn];
        const float wc0 = W1[256 * 128 + nn];
        const float wc1 = W1[257 * 128 + nn];
        #pragma unroll
        for (int r = 0; r < 4; ++r) {
            const int rr = g * 4 + r;
            const float h = fmaxf(C1[nt][r] + bb + ef0[r] * wc0 + ef1[r] * wc1, 0.0f);
            *(_Float16*)(h1base + rr * 256 + ((nn * 2) ^ (rr << 4))) = (_Float16)h;
        }
    }

    // ---- layer 2: [16,128] x [128,64]
    f32x4 C2[4];
    #pragma unroll
    for (int nt = 0; nt < 4; ++nt) C2[nt] = (f32x4){0.f, 0.f, 0.f, 0.f};
    #pragma unroll
    for (int kk = 0; kk < 4; ++kk) {
        const int k0b = kk * 64 + g * 16;
        const f16x8 a = *(const f16x8*)(h1base + c * 256 + (k0b ^ (c << 4)));
        #pragma unroll
        for (int nt = 0; nt < 4; ++nt) {
            const f16x8 bf = *(const f16x8*)(w2p + ((nt * 4 + kk) << 9) + lane * 8);
            C2[nt] = __builtin_amdgcn_mfma_f32_16x16x32_f16(a, bf, C2[nt], 0, 0, 0);
        }
    }

    // ---- layer 3: relu(h2) @ W3 + b3, 16-lane tree reduce
    const float bb3 = b3[0];
    #pragma unroll
    for (int r = 0; r < 4; ++r) {
        float acc = 0.0f;
        #pragma unroll
        for (int nt = 0; nt < 4; ++nt) {
            const int n2 = nt * 16 + c;
            acc += fmaxf(C2[nt][r] + b2[n2], 0.0f) * W3[n2];
        }
        acc += __shfl_xor(acc, 1);
        acc += __shfl_xor(acc, 2);
        acc += __shfl_xor(acc, 4);
        acc += __shfl_xor(acc, 8);
        const int m = base + g * 4 + r;
        if (c == 0 && m < ne) out[m] = acc + bb3;
    }
}

// ---------------------------------------------------------------------------
extern "C" void kernel_launch(void* const* d_in, const int* in_sizes, int n_in,
                              void* d_out, int out_size, void* d_ws, size_t ws_size,
                              hipStream_t stream) {
    const int*   type_idx   = (const int*)d_in[0];
    const int*   cat_idx    = (const int*)d_in[1];
    const int*   nbr_idx    = (const int*)d_in[2];
    const int*   nbr_mask   = (const int*)d_in[3];
    const int*   edges      = (const int*)d_in[4];
    const float* log_deg    = (const float*)d_in[5];
    const float* edge_feats = (const float*)d_in[6];
    const float* type_embed = (const float*)d_in[7];
    const float* cat0       = (const float*)d_in[8];
    const float* cat1       = (const float*)d_in[9];
    const float* deg_W      = (const float*)d_in[10];
    const float* deg_b      = (const float*)d_in[11];
    const float* proj_W     = (const float*)d_in[12];
    const float* proj_b     = (const float*)d_in[13];
    const float* attn_Wqkv  = (const float*)d_in[14];
    const float* attn_bqkv  = (const float*)d_in[15];
    const float* attn_Wo    = (const float*)d_in[16];
    const float* attn_bo    = (const float*)d_in[17];
    const float* eW1        = (const float*)d_in[18];
    const float* eb1        = (const float*)d_in[19];
    const float* eW2        = (const float*)d_in[20];
    const float* eb2        = (const float*)d_in[21];
    const float* eW3        = (const float*)d_in[22];
    const float* eb3        = (const float*)d_in[23];

    const int n  = in_sizes[0];        // N nodes
    const int ne = in_sizes[4] / 2;    // E edges
    float* out = (float*)d_out;

    // fp16 workspace buffers
    _Float16* xhA = (_Float16*)d_ws;                 // n*128
    _Float16* xhB = xhA + (size_t)n * HID;           // n*128
    _Float16* qh  = xhB + (size_t)n * HID;           // n*128
    _Float16* kvh = qh  + (size_t)n * HID;           // n*256 (k|v interleaved)
    _Float16* oh  = kvh + (size_t)n * 256;           // n*128
    _Float16* wpk = oh  + (size_t)n * HID;           // packed weights, 258048 halves
    int* mask = (int*)(wpk + 258048);
    _Float16* wqkvp[3] = {wpk, wpk + 49152, wpk + 98304};
    _Float16* wop[3]   = {wpk + 147456, wpk + 163840, wpk + 180224};
    _Float16* w1p    = wpk + 196608;
    _Float16* w2p    = wpk + 229376;
    _Float16* wprojp = wpk + 237568;

    prep_kernel<<<dim3(1008), dim3(256), 0, stream>>>(
        attn_Wqkv, attn_Wo, eW1, eW2, proj_W, wpk);

    const int gemm_grid = (n + 63) / 64;    // 4 waves x 16 nodes
    const int attn_grid = (n + 3) / 4;      // 4 waves x 1 node

    // fused encode + layer-0 qkv
    encode_qkv_kernel<<<dim3(gemm_grid), dim3(256), 0, stream>>>(
        type_idx, cat_idx, log_deg, type_embed, cat0, cat1, deg_W, deg_b,
        wprojp, proj_b, wqkvp[0], attn_bqkv,
        xhA, qh, kvh, n);
    attn_kernel<<<dim3(attn_grid), dim3(256), 0, stream>>>(
        qh, kvh, nbr_idx, nbr_mask, oh, mask, n);

    // layer transitions: (oh,mask,x_prev) -> x_next (+ qkv for next layer)
    projqkv_kernel<<<dim3(gemm_grid), dim3(256), 0, stream>>>(
        oh, mask, xhA, wop[0], attn_bo, wqkvp[1], attn_bqkv + 384,
        xhB, qh, kvh, 1, n);
    attn_kernel<<<dim3(attn_grid), dim3(256), 0, stream>>>(
        qh, kvh, nbr_idx, nbr_mask, oh, mask, n);

    projqkv_kernel<<<dim3(gemm_grid), dim3(256), 0, stream>>>(
        oh, mask, xhB, wop[1], attn_bo + 128, wqkvp[2], attn_bqkv + 768,
        xhA, qh, kvh, 1, n);
    attn_kernel<<<dim3(attn_grid), dim3(256), 0, stream>>>(
        qh, kvh, nbr_idx, nbr_mask, oh, mask, n);

    projqkv_kernel<<<dim3(gemm_grid), dim3(256), 0, stream>>>(
        oh, mask, xhA, wop[2], attn_bo + 256, nullptr, nullptr,
        xhB, nullptr, nullptr, 0, n);

    const int edge_grid = (ne + 63) / 64;   // 4 waves x 16 edges
    edge_mfma_kernel<<<dim3(edge_grid), dim3(256), 0, stream>>>(
        xhB, edges, edge_feats, w1p, w2p, eW1, eb1, eb2, eW3, eb3, out, ne);
}

// Round 11
// 403.970 us; speedup vs baseline: 17.3399x; 10.1181x over previous
//
#include <hip/hip_runtime.h>
#include <math.h>

#define HID 128

typedef _Float16 f16x8 __attribute__((ext_vector_type(8)));
typedef float    f32x4 __attribute__((ext_vector_type(4)));

static __device__ __forceinline__ float h_lo(unsigned p) {
    return (float)__builtin_bit_cast(_Float16, (unsigned short)p);
}
static __device__ __forceinline__ float h_hi(unsigned p) {
    return (float)__builtin_bit_cast(_Float16, (unsigned short)(p >> 16));
}
static __device__ __forceinline__ unsigned pack2h(float x, float y) {
    const unsigned short lx = __builtin_bit_cast(unsigned short, (_Float16)x);
    const unsigned short ly = __builtin_bit_cast(unsigned short, (_Float16)y);
    return ((unsigned)ly << 16) | lx;
}

// ---------------------------------------------------------------------------
// Kernel 0: pack ALL GEMM weights into fp16 MFMA B-fragment order.
// B-frag layout: [NT][KK][64 lane][8 j]; elem = W[k = KK*32+(ln>>4)*8+j][n = NT*16+(ln&15)]
// regions: wqkvp 3x[24][4] | wop 3x[8][4] | w1p [8][8] | w2p [4][4] | wprojp [8][5]
// ---------------------------------------------------------------------------
__global__ __launch_bounds__(256) void prep_kernel(
    const float* __restrict__ Wqkv, const float* __restrict__ Wo,
    const float* __restrict__ W1, const float* __restrict__ W2,
    const float* __restrict__ Wproj,
    _Float16* __restrict__ dst)
{
    const int idx = blockIdx.x * 256 + threadIdx.x;
    if (idx < 147456) {                     // wqkvp: 3 layers x 24nt x 4kk
        const int l = idx / 49152, t = idx % 49152;
        const int j = t & 7, ln = (t >> 3) & 63, kk = (t >> 9) & 3, nt = t >> 11;
        const int k = kk * 32 + (ln >> 4) * 8 + j, n = nt * 16 + (ln & 15);
        dst[idx] = (_Float16)Wqkv[((size_t)l * 128 + k) * 384 + n];
    } else if (idx < 196608) {              // wop: 3 layers x 8nt x 4kk
        const int t0 = idx - 147456;
        const int l = t0 / 16384, t = t0 % 16384;
        const int j = t & 7, ln = (t >> 3) & 63, kk = (t >> 9) & 3, nt = t >> 11;
        const int k = kk * 32 + (ln >> 4) * 8 + j, n = nt * 16 + (ln & 15);
        dst[idx] = (_Float16)Wo[((size_t)l * 128 + k) * 128 + n];
    } else if (idx < 229376) {              // w1p: 8nt x 8kk (k<256)
        const int t = idx - 196608;
        const int j = t & 7, ln = (t >> 3) & 63, kk = (t >> 9) & 7, nt = t >> 12;
        const int k = kk * 32 + (ln >> 4) * 8 + j, n = nt * 16 + (ln & 15);
        dst[idx] = (_Float16)W1[k * 128 + n];
    } else if (idx < 237568) {              // w2p: 4nt x 4kk
        const int t = idx - 229376;
        const int j = t & 7, ln = (t >> 3) & 63, kk = (t >> 9) & 3, nt = t >> 11;
        const int k = kk * 32 + (ln >> 4) * 8 + j, n = nt * 16 + (ln & 15);
        dst[idx] = (_Float16)W2[k * 64 + n];
    } else if (idx < 258048) {              // wprojp: 8nt x 5kk (k<160)
        const int t = idx - 237568;
        const int j = t & 7, ln = (t >> 3) & 63;
        const int blk = t >> 9;             // nt*5 + kk
        const int kk = blk % 5, nt = blk / 5;
        const int k = kk * 32 + (ln >> 4) * 8 + j, n = nt * 16 + (ln & 15);
        dst[idx] = (_Float16)Wproj[k * 128 + n];
    }
}

// tile swizzle: byte addr = row*256 + ((col*2) ^ (row<<4)), rows 0..15, cols 0..127
// full-coverage coalesced tile->global write, parameterized row stride (halves).
#define TILE_STORE_S(dst, rowstride)                                           \
    _Pragma("unroll")                                                          \
    for (int t = 0; t < 4; ++t) {                                              \
        const int lr  = t * 4 + (lane >> 4);                                   \
        const int j16 = lane & 15;                                             \
        const f16x8 v = *(const f16x8*)(tb + lr * 256 + ((j16 * 16) ^ (lr << 4))); \
        if (base + lr < n)                                                     \
            *(f16x8*)((dst) + (size_t)(base + lr) * (rowstride) + j16 * 8) = v;\
    }

// qkv GEMM from A-frags a2[4] (K=128) -> q (stride 128) + interleaved kv rows
// kvh[node][0..127]=k, [128..255]=v  (one 512B row per node)
#define QKV_PHASE(A2, WQ, BQKV)                                                \
    {                                                                          \
        _Pragma("unroll")                                                      \
        for (int part = 0; part < 3; ++part) {                                 \
            f32x4 C[8];                                                        \
            _Pragma("unroll")                                                  \
            for (int nt = 0; nt < 8; ++nt) C[nt] = (f32x4){0.f, 0.f, 0.f, 0.f};\
            _Pragma("unroll")                                                  \
            for (int kk = 0; kk < 4; ++kk) {                                   \
                _Pragma("unroll")                                              \
                for (int nt = 0; nt < 8; ++nt) {                               \
                    const f16x8 bf = *(const f16x8*)((WQ) + (((part * 8 + nt) * 4 + kk) << 9) + lane * 8); \
                    C[nt] = __builtin_amdgcn_mfma_f32_16x16x32_f16((A2)[kk], bf, C[nt], 0, 0, 0); \
                }                                                              \
            }                                                                  \
            _Pragma("unroll")                                                  \
            for (int nt = 0; nt < 8; ++nt) {                                   \
                const int nn = nt * 16 + c;                                    \
                const float bb = (BQKV)[part * 128 + nn];                      \
                _Pragma("unroll")                                              \
                for (int r = 0; r < 4; ++r) {                                  \
                    const int rr = g * 4 + r;                                  \
                    *(_Float16*)(tb + rr * 256 + ((nn * 2) ^ (rr << 4))) = (_Float16)(C[nt][r] + bb); \
                }                                                              \
            }                                                                  \
            if (part == 0)      { TILE_STORE_S(qh, 128) }                      \
            else if (part == 1) { TILE_STORE_S(kvh, 256) }                     \
            else                { TILE_STORE_S(kvh + 128, 256) }               \
        }                                                                      \
    }

// ---------------------------------------------------------------------------
// Kernel 1: FUSED node-encode + layer-0 qkv.  Wave = 16 nodes.
// ---------------------------------------------------------------------------
__global__ __launch_bounds__(256) void encode_qkv_kernel(
    const int* __restrict__ type_idx, const int* __restrict__ cat_idx,
    const float* __restrict__ log_deg,
    const float* __restrict__ type_embed, const float* __restrict__ cat0,
    const float* __restrict__ cat1, const float* __restrict__ deg_W,
    const float* __restrict__ deg_b,
    const _Float16* __restrict__ wprojp, const float* __restrict__ proj_b,
    const _Float16* __restrict__ wq, const float* __restrict__ bqkv,
    _Float16* __restrict__ xh,
    _Float16* __restrict__ qh, _Float16* __restrict__ kvh,
    int n)
{
    __shared__ __align__(16) _Float16 tile[4][16 * 128];
    const int wave = threadIdx.x >> 6;
    const int lane = threadIdx.x & 63;
    const int g = lane >> 4, c = lane & 15;
    const int base = (blockIdx.x * 4 + wave) * 16;
    if (base >= n) return;
    const int arow = min(base + c, n - 1);
    char* const tb = (char*)&tile[wave][0];

    // ---- build A-frags for K=160 feats
    const int  ti = type_idx[arow];
    const int  c0 = cat_idx[arow * 2 + 0];
    const int  c1 = cat_idx[arow * 2 + 1];
    const float ld = log_deg[arow];
    f16x8 a[5];
    {
        const float* srcs[4] = {
            type_embed + ti * 64 + g * 8,        // kk=0: feats[0..31]
            type_embed + ti * 64 + 32 + g * 8,   // kk=1: feats[32..63]
            cat0 + c0 * 32 + g * 8,              // kk=2: feats[64..95]
            cat1 + c1 * 32 + g * 8,              // kk=3: feats[96..127]
        };
        #pragma unroll
        for (int kk = 0; kk < 4; ++kk) {
            const float4 v0 = *(const float4*)(srcs[kk]);
            const float4 v1 = *(const float4*)(srcs[kk] + 4);
            a[kk] = (f16x8){(_Float16)v0.x, (_Float16)v0.y, (_Float16)v0.z, (_Float16)v0.w,
                            (_Float16)v1.x, (_Float16)v1.y, (_Float16)v1.z, (_Float16)v1.w};
        }
        const float4 w0 = *(const float4*)(deg_W + g * 8);
        const float4 w1 = *(const float4*)(deg_W + g * 8 + 4);
        const float4 d0 = *(const float4*)(deg_b + g * 8);
        const float4 d1 = *(const float4*)(deg_b + g * 8 + 4);
        a[4] = (f16x8){
            (_Float16)fmaxf(ld * w0.x + d0.x, 0.f), (_Float16)fmaxf(ld * w0.y + d0.y, 0.f),
            (_Float16)fmaxf(ld * w0.z + d0.z, 0.f), (_Float16)fmaxf(ld * w0.w + d0.w, 0.f),
            (_Float16)fmaxf(ld * w1.x + d1.x, 0.f), (_Float16)fmaxf(ld * w1.y + d1.y, 0.f),
            (_Float16)fmaxf(ld * w1.z + d1.z, 0.f), (_Float16)fmaxf(ld * w1.w + d1.w, 0.f)};
    }

    // ---- proj: 5kk x 8nt MFMAs
    f32x4 Cp[8];
    #pragma unroll
    for (int nt = 0; nt < 8; ++nt) Cp[nt] = (f32x4){0.f, 0.f, 0.f, 0.f};
    #pragma unroll
    for (int kk = 0; kk < 5; ++kk) {
        #pragma unroll
        for (int nt = 0; nt < 8; ++nt) {
            const f16x8 bf = *(const f16x8*)(wprojp + ((nt * 5 + kk) << 9) + lane * 8);
            Cp[nt] = __builtin_amdgcn_mfma_f32_16x16x32_f16(a[kk], bf, Cp[nt], 0, 0, 0);
        }
    }
    #pragma unroll
    for (int nt = 0; nt < 8; ++nt) {
        const int nn = nt * 16 + c;
        const float bb = proj_b[nn];
        #pragma unroll
        for (int r = 0; r < 4; ++r) {
            const int rr = g * 4 + r;
            *(_Float16*)(tb + rr * 256 + ((nn * 2) ^ (rr << 4))) = (_Float16)(Cp[nt][r] + bb);
        }
    }
    TILE_STORE_S(xh, 128)

    // ---- layer-0 qkv from the tile
    f16x8 a2[4];
    #pragma unroll
    for (int kk = 0; kk < 4; ++kk)
        a2[kk] = *(const f16x8*)(tb + c * 256 + ((kk * 64 + g * 16) ^ (c << 4)));
    QKV_PHASE(a2, wq, bqkv)
}

// ---------------------------------------------------------------------------
// Kernel 2: fused out-proj (+fallback+relu) and optional next-layer qkv.
// ---------------------------------------------------------------------------
__global__ __launch_bounds__(256) void projqkv_kernel(
    const _Float16* __restrict__ oh, const int* __restrict__ mask,
    const _Float16* __restrict__ xh_prev,
    const _Float16* __restrict__ wo, const float* __restrict__ bo,
    const _Float16* __restrict__ wq, const float* __restrict__ bqkv,
    _Float16* __restrict__ xh_next,
    _Float16* __restrict__ qh, _Float16* __restrict__ kvh,
    int do_qkv, int n)
{
    __shared__ __align__(16) _Float16 tile[4][16 * 128];
    const int wave = threadIdx.x >> 6;
    const int lane = threadIdx.x & 63;
    const int g = lane >> 4, c = lane & 15;
    const int base = (blockIdx.x * 4 + wave) * 16;
    if (base >= n) return;
    const int arow = min(base + c, n - 1);
    char* const tb = (char*)&tile[wave][0];

    // ---- phase 1: o @ Wo
    f32x4 Cp[8];
    #pragma unroll
    for (int nt = 0; nt < 8; ++nt) Cp[nt] = (f32x4){0.f, 0.f, 0.f, 0.f};
    #pragma unroll
    for (int kk = 0; kk < 4; ++kk) {
        const f16x8 a = *(const f16x8*)(oh + (size_t)arow * 128 + kk * 32 + g * 8);
        #pragma unroll
        for (int nt = 0; nt < 8; ++nt) {
            const f16x8 bf = *(const f16x8*)(wo + ((nt * 4 + kk) << 9) + lane * 8);
            Cp[nt] = __builtin_amdgcn_mfma_f32_16x16x32_f16(a, bf, Cp[nt], 0, 0, 0);
        }
    }
    int mk[4]; int rrow[4];
    #pragma unroll
    for (int r = 0; r < 4; ++r) {
        rrow[r] = min(base + g * 4 + r, n - 1);
        mk[r] = mask[rrow[r]];
    }
    #pragma unroll
    for (int nt = 0; nt < 8; ++nt) {
        const int nn = nt * 16 + c;
        const float bb = bo[nn];
        #pragma unroll
        for (int r = 0; r < 4; ++r) {
            float val = Cp[nt][r] + bb;
            if (!mk[r]) val = (float)xh_prev[(size_t)rrow[r] * 128 + nn];
            val = fmaxf(val, 0.0f);
            const int rr = g * 4 + r;
            *(_Float16*)(tb + rr * 256 + ((nn * 2) ^ (rr << 4))) = (_Float16)val;
        }
    }
    // write x_next coalesced (full 128 cols)
    TILE_STORE_S(xh_next, 128)
    if (!do_qkv) return;

    // ---- phase 2: x_next @ Wqkv (A-frags read from tile BEFORE overwriting it)
    f16x8 a2[4];
    #pragma unroll
    for (int kk = 0; kk < 4; ++kk)
        a2[kk] = *(const f16x8*)(tb + c * 256 + ((kk * 64 + g * 16) ^ (c << 4)));
    QKV_PHASE(a2, wq, bqkv)
}

// ---------------------------------------------------------------------------
// Kernel 3: attention core.  Wave per node.  STRAIGHT-LINE code, no branches:
// invalid neighbors gather the node's OWN kv row (address select, v_cndmask) —
// same address as the c=0 load -> L1 hit, no L2/L3 traffic.  Arrays stay in
// registers (rounds 8/9 proved ANY control flow around these loads spills).
// ---------------------------------------------------------------------------
__global__ __launch_bounds__(256) void attn_kernel(
    const _Float16* __restrict__ qh, const _Float16* __restrict__ kvh,
    const int* __restrict__ nbr_idx, const int* __restrict__ nbr_mask,
    _Float16* __restrict__ oh, int* __restrict__ mask_out, int n)
{
    const int wave = threadIdx.x >> 6;
    const int lane = threadIdx.x & 63;
    const float scale = 0.17677669529663687f;   // 1/sqrt(32)
    const int node = blockIdx.x * 4 + wave;
    if (node >= n) return;

    const unsigned qq = *(const unsigned*)(qh + (size_t)node * HID + lane * 2);
    const float qx = h_lo(qq), qy = h_hi(qq);

    unsigned kw[17], vw[17];
    int valid[17];
    valid[0] = 1;
    {
        const _Float16* kv = kvh + (size_t)node * 256;
        kw[0] = *(const unsigned*)(kv + lane * 2);
        vw[0] = *(const unsigned*)(kv + 128 + lane * 2);
    }
    int anyn = 0;
    #pragma unroll
    for (int c = 1; c < 17; ++c) {
        const int raw = nbr_idx[node * 16 + (c - 1)];
        const int vld = nbr_mask[node * 16 + (c - 1)];
        valid[c] = vld;
        anyn |= vld;
        const int cidx = vld ? raw : node;           // address select, no branch
        const _Float16* kv = kvh + (size_t)cidx * 256;
        kw[c] = *(const unsigned*)(kv + lane * 2);
        vw[c] = *(const unsigned*)(kv + 128 + lane * 2);
    }
    if (lane == 0) mask_out[node] = anyn;

    float s[17];
    #pragma unroll
    for (int c = 0; c < 17; ++c) {
        float p = qx * h_lo(kw[c]) + qy * h_hi(kw[c]);
        p += __shfl_xor(p, 1);
        p += __shfl_xor(p, 2);
        p += __shfl_xor(p, 4);
        p += __shfl_xor(p, 8);
        s[c] = valid[c] ? p * scale : -1e9f;
    }
    float mx = s[0];
    #pragma unroll
    for (int c = 1; c < 17; ++c) mx = fmaxf(mx, s[c]);
    float sum = 0.0f;
    #pragma unroll
    for (int c = 0; c < 17; ++c) { s[c] = __expf(s[c] - mx); sum += s[c]; }
    const float inv = 1.0f / sum;
    float ox = 0.0f, oy = 0.0f;
    #pragma unroll
    for (int c = 0; c < 17; ++c) {
        const float a = s[c] * inv;
        ox += a * h_lo(vw[c]);
        oy += a * h_hi(vw[c]);
    }
    *(unsigned*)(oh + (size_t)node * HID + lane * 2) = pack2h(ox, oy);
}

// ---------------------------------------------------------------------------
// Kernel 4: edge MLP via fp16 MFMA.
// ---------------------------------------------------------------------------
__global__ __launch_bounds__(256) void edge_mfma_kernel(
    const _Float16* __restrict__ xh,          // [N][128] fp16 final x
    const int* __restrict__ edges,
    const float* __restrict__ edge_feats,
    const _Float16* __restrict__ w1p,         // packed B-frags, 32768
    const _Float16* __restrict__ w2p,         // packed B-frags, 8192
    const float* __restrict__ W1,             // fp32 (rows 256,257 used)
    const float* __restrict__ b1,
    const float* __restrict__ b2,
    const float* __restrict__ W3, const float* __restrict__ b3,
    float* __restrict__ out, int ne)
{
    __shared__ __align__(16) _Float16 h1s[4][16 * 128];
    const int wave = threadIdx.x >> 6;
    const int lane = threadIdx.x & 63;
    const int g = lane >> 4, c = lane & 15;
    const int base = (blockIdx.x * 4 + wave) * 16;
    if (base >= ne) return;

    const int erow = min(base + c, ne - 1);
    const int e0 = edges[erow * 2 + 0];
    const int e1 = edges[erow * 2 + 1];

    // ---- layer 1: [16,256] x [256,128]
    f32x4 C1[8];
    #pragma unroll
    for (int nt = 0; nt < 8; ++nt) C1[nt] = (f32x4){0.f, 0.f, 0.f, 0.f};
    #pragma unroll
    for (int kk = 0; kk < 8; ++kk) {
        const int node = (kk < 4) ? e0 : e1;
        const f16x8 a = *(const f16x8*)(xh + (size_t)node * 128 + (kk & 3) * 32 + g * 8);
        #pragma unroll
        for (int nt = 0; nt < 8; ++nt) {
            const f16x8 bf = *(const f16x8*)(w1p + ((nt * 8 + kk) << 9) + lane * 8);
            C1[nt] = __builtin_amdgcn_mfma_f32_16x16x32_f16(a, bf, C1[nt], 0, 0, 0);
        }
    }

    // ---- epilogue 1: + b1 + ef @ W1[256:258] ; relu ; fp16 -> swizzled LDS
    float ef0[4], ef1[4];
    #pragma unroll
    for (int r = 0; r < 4; ++r) {
        const int m = min(base + g * 4 + r, ne - 1);
        ef0[r] = edge_feats[(size_t)m * 2 + 0];
        ef1[r] = edge_feats[(size_t)m * 2 + 1];
    }
    char* const h1base = (char*)&h1s[wave][0];
    #pragma unroll
    for (int nt = 0; nt < 8; ++nt) {
        const int nn  = nt * 16 + c;
        const float bb  = b1[nn];
        const float wc0 = W1[256 * 128 + nn];
        const float wc1 = W1[257 * 128 + nn];
        #pragma unroll
        for (int r = 0; r < 4; ++r) {
            const int rr = g * 4 + r;
            const float h = fmaxf(C1[nt][r] + bb + ef0[r] * wc0 + ef1[r] * wc1, 0.0f);
            *(_Float16*)(h1base + rr * 256 + ((nn * 2) ^ (rr << 4))) = (_Float16)h;
        }
    }

    // ---- layer 2: [16,128] x [128,64]
    f32x4 C2[4];
    #pragma unroll
    for (int nt = 0; nt < 4; ++nt) C2[nt] = (f32x4){0.f, 0.f, 0.f, 0.f};
    #pragma unroll
    for (int kk = 0; kk < 4; ++kk) {
        const int k0b = kk * 64 + g * 16;
        const f16x8 a = *(const f16x8*)(h1base + c * 256 + (k0b ^ (c << 4)));
        #pragma unroll
        for (int nt = 0; nt < 4; ++nt) {
            const f16x8 bf = *(const f16x8*)(w2p + ((nt * 4 + kk) << 9) + lane * 8);
            C2[nt] = __builtin_amdgcn_mfma_f32_16x16x32_f16(a, bf, C2[nt], 0, 0, 0);
        }
    }

    // ---- layer 3: relu(h2) @ W3 + b3, 16-lane tree reduce
    const float bb3 = b3[0];
    #pragma unroll
    for (int r = 0; r < 4; ++r) {
        float acc = 0.0f;
        #pragma unroll
        for (int nt = 0; nt < 4; ++nt) {
            const int n2 = nt * 16 + c;
            acc += fmaxf(C2[nt][r] + b2[n2], 0.0f) * W3[n2];
        }
        acc += __shfl_xor(acc, 1);
        acc += __shfl_xor(acc, 2);
        acc += __shfl_xor(acc, 4);
        acc += __shfl_xor(acc, 8);
        const int m = base + g * 4 + r;
        if (c == 0 && m < ne) out[m] = acc + bb3;
    }
}

// ---------------------------------------------------------------------------
extern "C" void kernel_launch(void* const* d_in, const int* in_sizes, int n_in,
                              void* d_out, int out_size, void* d_ws, size_t ws_size,
                              hipStream_t stream) {
    const int*   type_idx   = (const int*)d_in[0];
    const int*   cat_idx    = (const int*)d_in[1];
    const int*   nbr_idx    = (const int*)d_in[2];
    const int*   nbr_mask   = (const int*)d_in[3];
    const int*   edges      = (const int*)d_in[4];
    const float* log_deg    = (const float*)d_in[5];
    const float* edge_feats = (const float*)d_in[6];
    const float* type_embed = (const float*)d_in[7];
    const float* cat0       = (const float*)d_in[8];
    const float* cat1       = (const float*)d_in[9];
    const float* deg_W      = (const float*)d_in[10];
    const float* deg_b      = (const float*)d_in[11];
    const float* proj_W     = (const float*)d_in[12];
    const float* proj_b     = (const float*)d_in[13];
    const float* attn_Wqkv  = (const float*)d_in[14];
    const float* attn_bqkv  = (const float*)d_in[15];
    const float* attn_Wo    = (const float*)d_in[16];
    const float* attn_bo    = (const float*)d_in[17];
    const float* eW1        = (const float*)d_in[18];
    const float* eb1        = (const float*)d_in[19];
    const float* eW2        = (const float*)d_in[20];
    const float* eb2        = (const float*)d_in[21];
    const float* eW3        = (const float*)d_in[22];
    const float* eb3        = (const float*)d_in[23];

    const int n  = in_sizes[0];        // N nodes
    const int ne = in_sizes[4] / 2;    // E edges
    float* out = (float*)d_out;

    // fp16 workspace buffers
    _Float16* xhA = (_Float16*)d_ws;                 // n*128
    _Float16* xhB = xhA + (size_t)n * HID;           // n*128
    _Float16* qh  = xhB + (size_t)n * HID;           // n*128
    _Float16* kvh = qh  + (size_t)n * HID;           // n*256 (k|v interleaved)
    _Float16* oh  = kvh + (size_t)n * 256;           // n*128
    _Float16* wpk = oh  + (size_t)n * HID;           // packed weights, 258048 halves
    int* mask = (int*)(wpk + 258048);
    _Float16* wqkvp[3] = {wpk, wpk + 49152, wpk + 98304};
    _Float16* wop[3]   = {wpk + 147456, wpk + 163840, wpk + 180224};
    _Float16* w1p    = wpk + 196608;
    _Float16* w2p    = wpk + 229376;
    _Float16* wprojp = wpk + 237568;

    prep_kernel<<<dim3(1008), dim3(256), 0, stream>>>(
        attn_Wqkv, attn_Wo, eW1, eW2, proj_W, wpk);

    const int gemm_grid = (n + 63) / 64;    // 4 waves x 16 nodes
    const int attn_grid = (n + 3) / 4;      // 4 waves x 1 node

    // fused encode + layer-0 qkv
    encode_qkv_kernel<<<dim3(gemm_grid), dim3(256), 0, stream>>>(
        type_idx, cat_idx, log_deg, type_embed, cat0, cat1, deg_W, deg_b,
        wprojp, proj_b, wqkvp[0], attn_bqkv,
        xhA, qh, kvh, n);
    attn_kernel<<<dim3(attn_grid), dim3(256), 0, stream>>>(
        qh, kvh, nbr_idx, nbr_mask, oh, mask, n);

    // layer transitions: (oh,mask,x_prev) -> x_next (+ qkv for next layer)
    projqkv_kernel<<<dim3(gemm_grid), dim3(256), 0, stream>>>(
        oh, mask, xhA, wop[0], attn_bo, wqkvp[1], attn_bqkv + 384,
        xhB, qh, kvh, 1, n);
    attn_kernel<<<dim3(attn_grid), dim3(256), 0, stream>>>(
        qh, kvh, nbr_idx, nbr_mask, oh, mask, n);

    projqkv_kernel<<<dim3(gemm_grid), dim3(256), 0, stream>>>(
        oh, mask, xhB, wop[1], attn_bo + 128, wqkvp[2], attn_bqkv + 768,
        xhA, qh, kvh, 1, n);
    attn_kernel<<<dim3(attn_grid), dim3(256), 0, stream>>>(
        qh, kvh, nbr_idx, nbr_mask, oh, mask, n);

    projqkv_kernel<<<dim3(gemm_grid), dim3(256), 0, stream>>>(
        oh, mask, xhA, wop[2], attn_bo + 256, nullptr, nullptr,
        xhB, nullptr, nullptr, 0, n);

    const int edge_grid = (ne + 63) / 64;   // 4 waves x 16 edges
    edge_mfma_kernel<<<dim3(edge_grid), dim3(256), 0, stream>>>(
        xhB, edges, edge_feats, w1p, w2p, eW1, eb1, eb2, eW3, eb3, out, ne);
}